// Round 1
// baseline (226.440 us; speedup 1.0000x reference)
//
#include <hip/hip_runtime.h>
#include <hip/hip_bf16.h>

#define T_LOCAL 2048
#define S_GLOBAL 4096
#define NQ 16
#define NK 8
#define HN 128

// 128^-0.5 * log2(e)
#define SCALE2 0.12753102541996022f

typedef __attribute__((ext_vector_type(8))) short short8;
typedef __attribute__((ext_vector_type(4))) float f32x4;

static __device__ __forceinline__ ushort f2bf(float x) {
  unsigned u = __builtin_bit_cast(unsigned, x);
  unsigned r = (u + 0x7fffu + ((u >> 16) & 1u)) >> 16;
  return (ushort)r;
}

// ---- pre-pass 1: K f32 -> bf16 (same layout [S][NK][HN]) ----
__global__ void k_convert(const float* __restrict__ K, ushort* __restrict__ Kb) {
  size_t i = ((size_t)blockIdx.x * 256 + threadIdx.x) * 4;
  float4 v = *(const float4*)(K + i);
  ushort4 o;
  o.x = f2bf(v.x); o.y = f2bf(v.y); o.z = f2bf(v.z); o.w = f2bf(v.w);
  *(ushort4*)(Kb + i) = o;
}

// ---- pre-pass 2: V f32 [S][NK][HN] -> Vt bf16 [NK][HN][S] (per-head transpose) ----
__global__ void v_transpose(const float* __restrict__ V, ushort* __restrict__ Vt) {
  int bid = blockIdx.x;            // 8 heads * 2 d-tiles * 64 p-tiles = 1024
  int h  = bid >> 7;
  int r  = bid & 127;
  int d0 = (r >> 6) << 6;          // 0 or 64
  int p0 = (r & 63) << 6;          // 0..4032
  __shared__ ushort tile[64][72];  // [d_local][p_local], padded
  int tx = threadIdx.x & 15, ty = threadIdx.x >> 4;
  #pragma unroll
  for (int it = 0; it < 4; ++it) {
    int p = p0 + it * 16 + ty;
    int d = tx * 4;
    float4 v = *(const float4*)(V + ((size_t)p * NK + h) * HN + d0 + d);
    tile[d + 0][it * 16 + ty] = f2bf(v.x);
    tile[d + 1][it * 16 + ty] = f2bf(v.y);
    tile[d + 2][it * 16 + ty] = f2bf(v.z);
    tile[d + 3][it * 16 + ty] = f2bf(v.w);
  }
  __syncthreads();
  #pragma unroll
  for (int it = 0; it < 4; ++it) {
    int d  = it * 16 + ty;
    int pb = tx * 4;
    ushort4 o;
    o.x = tile[d][pb + 0]; o.y = tile[d][pb + 1];
    o.z = tile[d][pb + 2]; o.w = tile[d][pb + 3];
    *(ushort4*)(Vt + ((size_t)h * HN + d0 + d) * S_GLOBAL + p0 + pb) = o;
  }
}

// ---- main attention kernel ----
// grid: 16 heads * 32 q-tiles(64 rows) = 512 blocks, 256 threads (4 waves)
// wave w owns q rows [t0 + 16w, t0 + 16w + 15] of head `head`.
__global__ __launch_bounds__(256, 2)
void attn_kernel(const float* __restrict__ Q, const ushort* __restrict__ Kb,
                 const ushort* __restrict__ Vt, float* __restrict__ Out) {
  __shared__ ushort Pl[4][16][56];   // per-wave P^T staging, padded row = 112B

  const int lane = threadIdx.x & 63;
  const int w    = threadIdx.x >> 6;
  const int qcol = lane & 15;        // q row within wave / D row for V-frag / key row for K-frag
  const int g    = lane >> 4;        // 4-lane group

  const int bid  = blockIdx.x;
  const int head = bid >> 5;
  const int kvh  = head >> 1;
  const int t0   = (bid & 31) << 6;
  const int tw   = t0 + w * 16;
  const int tq   = tw + qcol;        // this lane's q row (local index)

  // Q fragments (used as B operand: col = q, k-slice = d)
  short8 qf[4];
  {
    const float* qb = Q + ((size_t)tq * NQ + head) * HN;
    #pragma unroll
    for (int ds = 0; ds < 4; ++ds) {
      const float4* p4 = (const float4*)(qb + ds * 32 + g * 8);
      float4 a = p4[0], b = p4[1];
      short8 f;
      f[0] = f2bf(a.x); f[1] = f2bf(a.y); f[2] = f2bf(a.z); f[3] = f2bf(a.w);
      f[4] = f2bf(b.x); f[5] = f2bf(b.y); f[6] = f2bf(b.z); f[7] = f2bf(b.w);
      qf[ds] = f;
    }
  }

  f32x4 acc[8];
  #pragma unroll
  for (int i = 0; i < 8; ++i) acc[i] = (f32x4){0.f, 0.f, 0.f, 0.f};
  float m_run = -1e30f, l_run = 0.f;

  const ushort* Vrow = Vt + (size_t)kvh * HN * S_GLOBAL;
  ushort* prow = &Pl[w][qcol][0];

  auto tile_step = [&](int p0, bool needmask, bool anti) {
    // K A-fragments: row = key (qcol), k-slice = d   (8 x 16B loads)
    short8 kf[2][4];
    #pragma unroll
    for (int sub = 0; sub < 2; ++sub) {
      const ushort* kp = Kb + ((size_t)(p0 + sub * 16 + qcol) * NK + kvh) * HN + g * 8;
      #pragma unroll
      for (int ds = 0; ds < 4; ++ds)
        kf[sub][ds] = *(const short8*)(kp + ds * 32);
    }
    // V^T A-fragments: row = d (qcol), k-slice = keys  (issued early, 8 x 16B)
    short8 vf[8];
    #pragma unroll
    for (int db = 0; db < 8; ++db)
      vf[db] = *(const short8*)(Vrow + (size_t)(db * 16 + qcol) * S_GLOBAL + p0 + g * 8);

    // S^T = K * Q^T : D[key][q], key = 16*sub + 4g + r, q = qcol
    f32x4 st[2];
    st[0] = (f32x4){0.f, 0.f, 0.f, 0.f};
    st[1] = (f32x4){0.f, 0.f, 0.f, 0.f};
    #pragma unroll
    for (int sub = 0; sub < 2; ++sub)
      #pragma unroll
      for (int ds = 0; ds < 4; ++ds)
        st[sub] = __builtin_amdgcn_mfma_f32_16x16x32_bf16(kf[sub][ds], qf[ds], st[sub], 0, 0, 0);

    float s[8];
    #pragma unroll
    for (int sub = 0; sub < 2; ++sub) {
      #pragma unroll
      for (int r = 0; r < 4; ++r) {
        float sv = st[sub][r] * SCALE2;
        if (needmask) {
          int p = p0 + sub * 16 + g * 4 + r;
          bool ok = anti ? (p >= tq + 2049) : (p <= tq);
          sv = ok ? sv : -INFINITY;
        }
        s[sub * 4 + r] = sv;
      }
    }

    // online softmax (4-lane-group reduce over key axis)
    float mt = s[0];
    #pragma unroll
    for (int i = 1; i < 8; ++i) mt = fmaxf(mt, s[i]);
    mt = fmaxf(mt, __shfl_xor(mt, 16));
    mt = fmaxf(mt, __shfl_xor(mt, 32));
    float mnew = fmaxf(m_run, mt);
    float fsc  = __builtin_amdgcn_exp2f(m_run - mnew);
    float pv[8];
    float ps = 0.f;
    #pragma unroll
    for (int i = 0; i < 8; ++i) { pv[i] = __builtin_amdgcn_exp2f(s[i] - mnew); ps += pv[i]; }
    ps += __shfl_xor(ps, 16);
    ps += __shfl_xor(ps, 32);
    l_run = l_run * fsc + ps;
    m_run = mnew;
    #pragma unroll
    for (int i = 0; i < 8; ++i) acc[i] *= fsc;

    // P^T -> LDS (keys this lane owns: sub*16 + 4g + 0..3), then read B-frag (8 consecutive keys)
    unsigned lo0 = (unsigned)f2bf(pv[0]) | ((unsigned)f2bf(pv[1]) << 16);
    unsigned hi0 = (unsigned)f2bf(pv[2]) | ((unsigned)f2bf(pv[3]) << 16);
    unsigned lo1 = (unsigned)f2bf(pv[4]) | ((unsigned)f2bf(pv[5]) << 16);
    unsigned hi1 = (unsigned)f2bf(pv[6]) | ((unsigned)f2bf(pv[7]) << 16);
    *(uint2*)(prow + g * 4)      = make_uint2(lo0, hi0);
    *(uint2*)(prow + 16 + g * 4) = make_uint2(lo1, hi1);
    short8 pf = *(const short8*)(prow + g * 8);

    // O^T += V^T * P^T : D[d][q], d = db*16 + 4g + r, q = qcol
    #pragma unroll
    for (int db = 0; db < 8; ++db)
      acc[db] = __builtin_amdgcn_mfma_f32_16x16x32_bf16(vf[db], pf, acc[db], 0, 0, 0);
  };

  const int twlast = tw + 15;
  // causal segment: p <= tq
  int cbeg = (t0 >= T_LOCAL / 2) ? 1024 : 0;
  for (int p0 = cbeg; p0 <= twlast; p0 += 32)
    tile_step(p0, p0 + 31 > tw, false);
  // anti segment (second half only): p >= tq + 2049
  if (t0 >= T_LOCAL / 2) {
    int abeg = (tw + 2049) & ~31;
    for (int p0 = abeg; p0 < S_GLOBAL; p0 += 32)
      tile_step(p0, p0 < tw + 2064, true);
  }

  // epilogue: Out[tq][head*128 + d], d = db*16 + 4g + r
  float inv = 1.0f / l_run;
  float* ob = Out + (size_t)tq * (NQ * HN) + head * HN + g * 4;
  #pragma unroll
  for (int db = 0; db < 8; ++db) {
    float4 o;
    o.x = acc[db][0] * inv; o.y = acc[db][1] * inv;
    o.z = acc[db][2] * inv; o.w = acc[db][3] * inv;
    *(float4*)(ob + db * 16) = o;
  }
}

extern "C" void kernel_launch(void* const* d_in, const int* in_sizes, int n_in,
                              void* d_out, int out_size, void* d_ws, size_t ws_size,
                              hipStream_t stream) {
  const float* Q = (const float*)d_in[0];
  const float* K = (const float*)d_in[1];
  const float* V = (const float*)d_in[2];
  float* Out = (float*)d_out;

  ushort* Kb = (ushort*)d_ws;                         // 8 MB
  ushort* Vt = Kb + (size_t)S_GLOBAL * NK * HN;       // 8 MB

  k_convert<<<dim3((S_GLOBAL * NK * HN) / (256 * 4)), dim3(256), 0, stream>>>(K, Kb);
  v_transpose<<<dim3(NK * 2 * (S_GLOBAL / 64)), dim3(256), 0, stream>>>(V, Vt);
  attn_kernel<<<dim3(512), dim3(256), 0, stream>>>(Q, Kb, Vt, Out);
}